// Round 15
// baseline (293.771 us; speedup 1.0000x reference)
//
#include <hip/hip_runtime.h>
#include <hip/hip_bf16.h>

#define NN 100000
#define EE 800000
#define DALL 256
#define NEG 0.2f

#define CNT_BLOCKS 3125     // ceil(EE/256)
#define CVTW_BLOCKS 128     // 8 x 16
#define CVTX_BLOCKS 2048

typedef __attribute__((ext_vector_type(8))) short bf16x8;
typedef __attribute__((ext_vector_type(4))) float f32x4;

static __device__ __forceinline__ ushort f2b(float f) {
    __hip_bfloat16 h = __float2bfloat16(f);
    return *reinterpret_cast<ushort*>(&h);
}
static __device__ __forceinline__ float bits2f(unsigned q) {
    union { float f; unsigned v; } c; c.v = q; return c.f;
}
// packed bf16x2 -> 2 floats: 1 VALU op per float
static __device__ __forceinline__ void unpack8(uint4 u, float* v) {
    v[0] = bits2f(u.x << 16); v[1] = bits2f(u.x & 0xffff0000u);
    v[2] = bits2f(u.y << 16); v[3] = bits2f(u.y & 0xffff0000u);
    v[4] = bits2f(u.z << 16); v[5] = bits2f(u.z & 0xffff0000u);
    v[6] = bits2f(u.w << 16); v[7] = bits2f(u.w & 0xffff0000u);
}

// ---- fused init: count_deg | cvt_W | cvt_x, partitioned by blockIdx -------
__global__ __launch_bounds__(256) void fused_init(
    const float* __restrict__ x, const float* __restrict__ Wl,
    const float* __restrict__ Wr, const int* __restrict__ dst,
    ushort* __restrict__ xb, ushort* __restrict__ Wt, int* __restrict__ cnt)
{
    __shared__ float tile[32][33];
    int b = blockIdx.x;
    if (b < CNT_BLOCKS) {
        int e = b * 256 + threadIdx.x;
        if (e < EE) atomicAdd(&cnt[dst[e]], 1);
        return;
    }
    b -= CNT_BLOCKS;
    if (b < CVTW_BLOCKS) {
        int kt = (b & 7) * 32, nt = (b >> 3) * 32;
        int tx = threadIdx.x & 31, ty = threadIdx.x >> 5;
#pragma unroll
        for (int i = 0; i < 32; i += 8) {
            int k = kt + ty + i, n = nt + tx;
            float v = (n < 256) ? Wl[(size_t)k * 256 + n] : Wr[(size_t)k * 256 + (n - 256)];
            tile[ty + i][tx] = v;
        }
        __syncthreads();
#pragma unroll
        for (int i = 0; i < 32; i += 8) {
            int n = nt + ty + i, k = kt + tx;
            Wt[(size_t)n * 256 + k] = f2b(tile[tx][ty + i]);
        }
        return;
    }
    b -= CVTW_BLOCKS;
    const int total = NN * DALL / 8;
    for (int i = b * 256 + threadIdx.x; i < total; i += CVTX_BLOCKS * 256) {
        f32x4 a = __builtin_nontemporal_load(reinterpret_cast<const f32x4*>(x) + i * 2);
        f32x4 c = __builtin_nontemporal_load(reinterpret_cast<const f32x4*>(x) + i * 2 + 1);
        uint4 o;
        o.x = f2b(a[0]) | ((unsigned)f2b(a[1]) << 16);
        o.y = f2b(a[2]) | ((unsigned)f2b(a[3]) << 16);
        o.z = f2b(c[0]) | ((unsigned)f2b(c[1]) << 16);
        o.w = f2b(c[2]) | ((unsigned)f2b(c[3]) << 16);
        reinterpret_cast<uint4*>(xb)[i] = o;
    }
}

// ------------- MFMA GEMM: 128 rows x 512 cols per block, 8 waves -----------
__global__ __launch_bounds__(512) void gemm_dual(
    const ushort* __restrict__ xb,   // [NN][256] bf16
    const ushort* __restrict__ Wt,   // [512][256] bf16 (B^T layout)
    const float* __restrict__ bl, const float* __restrict__ br,
    ushort* __restrict__ xl, ushort* __restrict__ xr)
{
    __shared__ __align__(16) ushort smemA[2][128 * 32];   // 8KB/buf
    __shared__ __align__(16) ushort smemB[2][512 * 32];   // 32KB/buf

    const int rowBase = blockIdx.x * 128;
    const int t = threadIdx.x, lane = t & 63, wave = t >> 6;
    const int wr  = (wave >> 2) * 64;     // 2 row groups (0,64)
    const int wcg = (wave & 3) * 128;     // 4 col groups (0,128,256,384)

    f32x4 acc[4][8];
#pragma unroll
    for (int m = 0; m < 4; ++m)
#pragma unroll
        for (int n = 0; n < 8; ++n) acc[m][n] = (f32x4){0.f, 0.f, 0.f, 0.f};

    auto STAGE = [&](int buf, int kb) {
        {   // A: 128x32 = 512 chunks of 16B, 1/thread
            int rc = t >> 2, slot = t & 3;
            int ga = rowBase + rc; if (ga >= NN) ga = NN - 1;
            const ushort* gp = xb + (size_t)ga * 256 + kb + slot * 8;
            ushort* lp = &smemA[buf][wave * 512];
            __builtin_amdgcn_global_load_lds(
                (const __attribute__((address_space(1))) unsigned int*)gp,
                (__attribute__((address_space(3))) unsigned int*)lp, 16, 0, 0);
        }
#pragma unroll
        for (int i = 0; i < 4; ++i) {   // B: 512x32 = 2048 chunks, 4/thread
            int c = i * 512 + t;
            int rc = c >> 2, slot = c & 3;
            const ushort* gp = Wt + (size_t)rc * 256 + kb + slot * 8;
            ushort* lp = &smemB[buf][(i * 512 + wave * 64) * 8];
            __builtin_amdgcn_global_load_lds(
                (const __attribute__((address_space(1))) unsigned int*)gp,
                (__attribute__((address_space(3))) unsigned int*)lp, 16, 0, 0);
        }
    };

    STAGE(0, 0);
    __syncthreads();

#pragma unroll
    for (int s = 0; s < 8; ++s) {
        if (s < 7) STAGE((s + 1) & 1, (s + 1) * 32);
        const ushort* A = smemA[s & 1];
        const ushort* B = smemB[s & 1];
        bf16x8 af[4], bfr[8];
#pragma unroll
        for (int m = 0; m < 4; ++m)
            af[m] = *reinterpret_cast<const bf16x8*>(
                &A[(wr + m * 16 + (lane & 15)) * 32 + (lane >> 4) * 8]);
#pragma unroll
        for (int n = 0; n < 8; ++n)
            bfr[n] = *reinterpret_cast<const bf16x8*>(
                &B[(wcg + n * 16 + (lane & 15)) * 32 + (lane >> 4) * 8]);
#pragma unroll
        for (int m = 0; m < 4; ++m)
#pragma unroll
            for (int n = 0; n < 8; ++n)
                acc[m][n] = __builtin_amdgcn_mfma_f32_16x16x32_bf16(
                    af[m], bfr[n], acc[m][n], 0, 0, 0);
        if (s < 7) __syncthreads();
    }

    const bool isL = (wcg < 256);
    ushort* OutP = isL ? xl : xr;
    const float* bvp = isL ? bl : br;
    const int cb0 = wcg & 255;

    int colLoc[8]; float bb[8];
#pragma unroll
    for (int n = 0; n < 8; ++n) {
        colLoc[n] = cb0 + n * 16 + (lane & 15);
        bb[n] = bvp[colLoc[n]];
    }
#pragma unroll
    for (int m = 0; m < 4; ++m) {
        int r0 = rowBase + wr + m * 16 + (lane >> 4) * 4;
#pragma unroll
        for (int r = 0; r < 4; ++r) {
            int row = r0 + r;
            if (row < NN) {
#pragma unroll
                for (int n = 0; n < 8; ++n)
                    OutP[(size_t)row * 256 + colLoc[n]] = f2b(acc[m][n][r] + bb[n]);
            }
        }
    }
}

// ------- fused scan: each block sums its prefix directly, then local scan --
__global__ __launch_bounds__(256) void scan_fused(const int* __restrict__ cnt,
                                                  int* __restrict__ rowptr)
{
    __shared__ int red[256];
    __shared__ int pre[256];
    int tb = threadIdx.x;

    // prefix base: sum of cnt[0 .. blockIdx.x*1024), int4-vectorized, L2-hot
    const int4* c4 = reinterpret_cast<const int4*>(cnt);
    int lim4 = blockIdx.x * 256;            // (blockIdx.x*1024)/4
    int s0 = 0;
    for (int i = tb; i < lim4; i += 256) {
        int4 v = c4[i];
        s0 += v.x + v.y + v.z + v.w;
    }
    red[tb] = s0; __syncthreads();
    for (int off = 128; off > 0; off >>= 1) {
        if (tb < off) red[tb] += red[tb + off];
        __syncthreads();
    }
    int base0 = red[0];

    // local exclusive scan of this block's 1024 counts
    int base = blockIdx.x * 1024 + tb * 4;
    int v[4]; int s = 0;
#pragma unroll
    for (int k = 0; k < 4; ++k) { int i = base + k; v[k] = (i < NN) ? cnt[i] : 0; s += v[k]; }
    pre[tb] = s; __syncthreads();
    for (int off = 1; off < 256; off <<= 1) {
        int tv = (tb >= off) ? pre[tb - off] : 0;
        __syncthreads();
        pre[tb] += tv;
        __syncthreads();
    }
    int excl = pre[tb] - s + base0;
#pragma unroll
    for (int k = 0; k < 4; ++k) {
        int i = base + k;
        if (i < NN) { rowptr[i] = excl; excl += v[k]; }
    }
}

// fill: rowptr doubles as cursor; post-fill rowptr[n] == orig rowptr[n+1]
__global__ __launch_bounds__(256) void fill_csr(const int* __restrict__ src,
                                                const int* __restrict__ dst,
                                                int* __restrict__ rowptr,
                                                int* __restrict__ srcs)
{
    int e = blockIdx.x * 256 + threadIdx.x;
    if (e >= EE) return;
    int pos = atomicAdd(&rowptr[dst[e]], 1);
    srcs[pos] = src[e];
}

// ------------- fused: score + softmax-agg + bias + residual + LN + ELU -----
// one wave per node; srcs via lane-window + shfl; lrelu = 0.6z + 0.4|z|
__global__ __launch_bounds__(256) void aggregate_finalize(
    const ushort* __restrict__ xl, const ushort* __restrict__ xr,
    const int* __restrict__ srcs, const int* __restrict__ rowptr,
    const float* __restrict__ att, const ushort* __restrict__ xb,
    const float* __restrict__ bias, const float* __restrict__ gamma,
    const float* __restrict__ beta, float* __restrict__ out)
{
    int node = blockIdx.x * 4 + (threadIdx.x >> 6);
    if (node >= NN) return;
    int lane = threadIdx.x & 63;
    int half = lane >> 5;
    int dl = lane & 31;          // dims [dl*8, dl*8+8)
    const int off = dl * 8;

    uint4 xru = *reinterpret_cast<const uint4*>(xr + (size_t)node * DALL + off);
    float xrv[8]; unpack8(xru, xrv);
    float a06[8], a04[8];        // 0.6*att, 0.4*att (lrelu = 0.6z + 0.4|z|)
    {
        float4 a0 = *reinterpret_cast<const float4*>(att + off);
        float4 a1 = *reinterpret_cast<const float4*>(att + off + 4);
        float av[8] = {a0.x, a0.y, a0.z, a0.w, a1.x, a1.y, a1.z, a1.w};
#pragma unroll
        for (int i = 0; i < 8; ++i) { a06[i] = 0.6f * av[i]; a04[i] = 0.4f * av[i]; }
    }

    int beg = node ? rowptr[node - 1] : 0;
    int end = rowptr[node];
    float a[8] = {0.f,0.f,0.f,0.f,0.f,0.f,0.f,0.f};
    float dsum = 0.f;

    for (int wbase = beg; wbase < end; wbase += 64) {
        int wdeg = end - wbase; if (wdeg > 64) wdeg = 64;
        int sidx = wbase + lane; if (sidx > EE - 1) sidx = EE - 1;
        int srcs_l = srcs[sidx];      // one load covers the whole window

        for (int rb = 0; rb < wdeg; rb += 4) {
            int rA = rb + half;
            int rB = rb + 2 + half;
            bool vA = rA < wdeg, vB = rB < wdeg;
            int sA = __shfl(srcs_l, vA ? rA : 0);
            int sB = __shfl(srcs_l, vB ? rB : 0);
            uint4 gA = *reinterpret_cast<const uint4*>(xl + (size_t)sA * DALL + off);
            uint4 gB = *reinterpret_cast<const uint4*>(xl + (size_t)sB * DALL + off);
            float vAv[8], vBv[8]; unpack8(gA, vAv); unpack8(gB, vBv);
            float pA = 0.f, pB = 0.f;
#pragma unroll
            for (int i = 0; i < 8; ++i) {
                float z = vAv[i] + xrv[i];
                pA += z * a06[i] + fabsf(z) * a04[i];      // 2 fma, abs free
                float z2 = vBv[i] + xrv[i];
                pB += z2 * a06[i] + fabsf(z2) * a04[i];
            }
            pA += __shfl_xor(pA, 1); pA += __shfl_xor(pA, 2);
            pB += __shfl_xor(pB, 1); pB += __shfl_xor(pB, 2);
            float peA = vA ? __expf(pA) : 0.f;
            float peB = vB ? __expf(pB) : 0.f;
#pragma unroll
            for (int i = 0; i < 8; ++i) a[i] += peA * vAv[i] + peB * vBv[i];
            dsum += peA + peB;
        }
    }

#pragma unroll
    for (int i = 0; i < 8; ++i) a[i] += __shfl_xor(a[i], 32);
    dsum += __shfl_xor(dsum, 32);
    float inv = dsum > 0.f ? 1.f / dsum : 0.f;

    uint4 xbu = *reinterpret_cast<const uint4*>(xb + (size_t)node * DALL + off);
    float xv[8]; unpack8(xbu, xv);
    float bvv[8], gvv[8], bev[8];
    {
        float4 b0 = *reinterpret_cast<const float4*>(bias + off);
        float4 b1 = *reinterpret_cast<const float4*>(bias + off + 4);
        bvv[0]=b0.x; bvv[1]=b0.y; bvv[2]=b0.z; bvv[3]=b0.w;
        bvv[4]=b1.x; bvv[5]=b1.y; bvv[6]=b1.z; bvv[7]=b1.w;
        float4 g0 = *reinterpret_cast<const float4*>(gamma + off);
        float4 g1 = *reinterpret_cast<const float4*>(gamma + off + 4);
        gvv[0]=g0.x; gvv[1]=g0.y; gvv[2]=g0.z; gvv[3]=g0.w;
        gvv[4]=g1.x; gvv[5]=g1.y; gvv[6]=g1.z; gvv[7]=g1.w;
        float4 e0 = *reinterpret_cast<const float4*>(beta + off);
        float4 e1 = *reinterpret_cast<const float4*>(beta + off + 4);
        bev[0]=e0.x; bev[1]=e0.y; bev[2]=e0.z; bev[3]=e0.w;
        bev[4]=e1.x; bev[5]=e1.y; bev[6]=e1.z; bev[7]=e1.w;
    }

    float y[8]; float sum = 0.f, sq = 0.f;
#pragma unroll
    for (int i = 0; i < 8; ++i) {
        y[i] = a[i] * inv + bvv[i] + xv[i];
        sum += y[i]; sq += y[i] * y[i];
    }
#pragma unroll
    for (int m = 1; m < 32; m <<= 1) {
        sum += __shfl_xor(sum, m);
        sq  += __shfl_xor(sq, m);
    }
    float mu  = sum * (1.0f / 256.0f);
    float var = sq * (1.0f / 256.0f) - mu * mu;
    float rr  = rsqrtf(var + 1e-5f);

    if (half == 0) {
        f32x4 o0, o1;
#pragma unroll
        for (int i = 0; i < 8; ++i) {
            float z = (y[i] - mu) * rr * gvv[i] + bev[i];
            float e = z > 0.f ? z : __expf(z) - 1.f;   // ELU via fast exp
            if (i < 4) o0[i] = e; else o1[i - 4] = e;
        }
        __builtin_nontemporal_store(o0,
            reinterpret_cast<f32x4*>(out + (size_t)node * DALL + off));
        __builtin_nontemporal_store(o1,
            reinterpret_cast<f32x4*>(out + (size_t)node * DALL + off + 4));
    }
}

extern "C" void kernel_launch(void* const* d_in, const int* in_sizes, int n_in,
                              void* d_out, int out_size, void* d_ws, size_t ws_size,
                              hipStream_t stream)
{
    const float* x    = (const float*)d_in[0];
    const int*   edge = (const int*)d_in[1];
    const float* Wl   = (const float*)d_in[2];
    const float* bl   = (const float*)d_in[3];
    const float* Wr   = (const float*)d_in[4];
    const float* br   = (const float*)d_in[5];
    const float* att  = (const float*)d_in[6];
    const float* bias = (const float*)d_in[7];
    const float* gamma= (const float*)d_in[8];
    const float* beta = (const float*)d_in[9];
    float* out = (float*)d_out;

    const int* srcIdx = edge;
    const int* dstIdx = edge + EE;

    ushort* xl = (ushort*)d_ws;                     // NN*256 bf16
    ushort* xr = xl + (size_t)NN * DALL;            // NN*256 bf16
    ushort* xb = xr + (size_t)NN * DALL;            // NN*256 bf16
    ushort* Wt = xb + (size_t)NN * DALL;            // 512*256 bf16
    int* rowptr = (int*)(Wt + 512 * 256);           // NN
    int* cnt    = rowptr + NN + 1;                  // NN
    int* srcs   = cnt + NN;                         // EE

    const int SCAN_NB = (NN + 1023) / 1024;         // 98

    hipMemsetAsync(cnt, 0, NN * sizeof(int), stream);
    fused_init<<<CNT_BLOCKS + CVTW_BLOCKS + CVTX_BLOCKS, 256, 0, stream>>>(
        x, Wl, Wr, dstIdx, xb, Wt, cnt);
    gemm_dual<<<(NN + 127) / 128, 512, 0, stream>>>(xb, Wt, bl, br, xl, xr);
    scan_fused<<<SCAN_NB, 256, 0, stream>>>(cnt, rowptr);
    fill_csr<<<(EE + 255) / 256, 256, 0, stream>>>(srcIdx, dstIdx, rowptr, srcs);
    aggregate_finalize<<<NN / 4, 256, 0, stream>>>(
        xl, xr, srcs, rowptr, att, xb, bias, gamma, beta, out);
}

// Round 16
// 279.334 us; speedup vs baseline: 1.0517x; 1.0517x over previous
//
#include <hip/hip_runtime.h>
#include <hip/hip_bf16.h>

#define NN 100000
#define EE 800000
#define DALL 256
#define NEG 0.2f

#define CNT_BLOCKS 3125     // ceil(EE/256)
#define CVTW_BLOCKS 128     // 8 x 16
#define CVTX_BLOCKS 2048

typedef __attribute__((ext_vector_type(8))) short bf16x8;
typedef __attribute__((ext_vector_type(4))) float f32x4;

static __device__ __forceinline__ ushort f2b(float f) {
    __hip_bfloat16 h = __float2bfloat16(f);
    return *reinterpret_cast<ushort*>(&h);
}
static __device__ __forceinline__ float b2f(ushort u) {
    union { float f; unsigned v; } c; c.v = ((unsigned)u) << 16; return c.f;
}
static __device__ __forceinline__ void unpack8(uint4 u, float* v) {
    v[0] = b2f((ushort)(u.x & 0xffff)); v[1] = b2f((ushort)(u.x >> 16));
    v[2] = b2f((ushort)(u.y & 0xffff)); v[3] = b2f((ushort)(u.y >> 16));
    v[4] = b2f((ushort)(u.z & 0xffff)); v[5] = b2f((ushort)(u.z >> 16));
    v[6] = b2f((ushort)(u.w & 0xffff)); v[7] = b2f((ushort)(u.w >> 16));
}

// ---- fused init: count_deg | cvt_W | cvt_x, partitioned by blockIdx -------
__global__ __launch_bounds__(256) void fused_init(
    const float* __restrict__ x, const float* __restrict__ Wl,
    const float* __restrict__ Wr, const int* __restrict__ dst,
    ushort* __restrict__ xb, ushort* __restrict__ Wt, int* __restrict__ cnt)
{
    __shared__ float tile[32][33];
    int b = blockIdx.x;
    if (b < CNT_BLOCKS) {
        int e = b * 256 + threadIdx.x;
        if (e < EE) atomicAdd(&cnt[dst[e]], 1);
        return;
    }
    b -= CNT_BLOCKS;
    if (b < CVTW_BLOCKS) {
        int kt = (b & 7) * 32, nt = (b >> 3) * 32;
        int tx = threadIdx.x & 31, ty = threadIdx.x >> 5;
#pragma unroll
        for (int i = 0; i < 32; i += 8) {
            int k = kt + ty + i, n = nt + tx;
            float v = (n < 256) ? Wl[(size_t)k * 256 + n] : Wr[(size_t)k * 256 + (n - 256)];
            tile[ty + i][tx] = v;
        }
        __syncthreads();
#pragma unroll
        for (int i = 0; i < 32; i += 8) {
            int n = nt + ty + i, k = kt + tx;
            Wt[(size_t)n * 256 + k] = f2b(tile[tx][ty + i]);
        }
        return;
    }
    b -= CVTW_BLOCKS;
    const int total = NN * DALL / 8;
    for (int i = b * 256 + threadIdx.x; i < total; i += CVTX_BLOCKS * 256) {
        f32x4 a = __builtin_nontemporal_load(reinterpret_cast<const f32x4*>(x) + i * 2);
        f32x4 c = __builtin_nontemporal_load(reinterpret_cast<const f32x4*>(x) + i * 2 + 1);
        uint4 o;
        o.x = f2b(a[0]) | ((unsigned)f2b(a[1]) << 16);
        o.y = f2b(a[2]) | ((unsigned)f2b(a[3]) << 16);
        o.z = f2b(c[0]) | ((unsigned)f2b(c[1]) << 16);
        o.w = f2b(c[2]) | ((unsigned)f2b(c[3]) << 16);
        reinterpret_cast<uint4*>(xb)[i] = o;
    }
}

// ------------- MFMA GEMM: 128 rows x 512 cols per block, 8 waves -----------
__global__ __launch_bounds__(512) void gemm_dual(
    const ushort* __restrict__ xb,   // [NN][256] bf16
    const ushort* __restrict__ Wt,   // [512][256] bf16 (B^T layout)
    const float* __restrict__ bl, const float* __restrict__ br,
    ushort* __restrict__ xl, ushort* __restrict__ xr)
{
    __shared__ __align__(16) ushort smemA[2][128 * 32];   // 8KB/buf
    __shared__ __align__(16) ushort smemB[2][512 * 32];   // 32KB/buf

    const int rowBase = blockIdx.x * 128;
    const int t = threadIdx.x, lane = t & 63, wave = t >> 6;
    const int wr  = (wave >> 2) * 64;     // 2 row groups (0,64)
    const int wcg = (wave & 3) * 128;     // 4 col groups (0,128,256,384)

    f32x4 acc[4][8];
#pragma unroll
    for (int m = 0; m < 4; ++m)
#pragma unroll
        for (int n = 0; n < 8; ++n) acc[m][n] = (f32x4){0.f, 0.f, 0.f, 0.f};

    auto STAGE = [&](int buf, int kb) {
        {   // A: 128x32 = 512 chunks of 16B, 1/thread
            int rc = t >> 2, slot = t & 3;
            int ga = rowBase + rc; if (ga >= NN) ga = NN - 1;
            const ushort* gp = xb + (size_t)ga * 256 + kb + slot * 8;
            ushort* lp = &smemA[buf][wave * 512];
            __builtin_amdgcn_global_load_lds(
                (const __attribute__((address_space(1))) unsigned int*)gp,
                (__attribute__((address_space(3))) unsigned int*)lp, 16, 0, 0);
        }
#pragma unroll
        for (int i = 0; i < 4; ++i) {   // B: 512x32 = 2048 chunks, 4/thread
            int c = i * 512 + t;
            int rc = c >> 2, slot = c & 3;
            const ushort* gp = Wt + (size_t)rc * 256 + kb + slot * 8;
            ushort* lp = &smemB[buf][(i * 512 + wave * 64) * 8];
            __builtin_amdgcn_global_load_lds(
                (const __attribute__((address_space(1))) unsigned int*)gp,
                (__attribute__((address_space(3))) unsigned int*)lp, 16, 0, 0);
        }
    };

    STAGE(0, 0);
    __syncthreads();

#pragma unroll
    for (int s = 0; s < 8; ++s) {
        if (s < 7) STAGE((s + 1) & 1, (s + 1) * 32);
        const ushort* A = smemA[s & 1];
        const ushort* B = smemB[s & 1];
        bf16x8 af[4], bfr[8];
#pragma unroll
        for (int m = 0; m < 4; ++m)
            af[m] = *reinterpret_cast<const bf16x8*>(
                &A[(wr + m * 16 + (lane & 15)) * 32 + (lane >> 4) * 8]);
#pragma unroll
        for (int n = 0; n < 8; ++n)
            bfr[n] = *reinterpret_cast<const bf16x8*>(
                &B[(wcg + n * 16 + (lane & 15)) * 32 + (lane >> 4) * 8]);
#pragma unroll
        for (int m = 0; m < 4; ++m)
#pragma unroll
            for (int n = 0; n < 8; ++n)
                acc[m][n] = __builtin_amdgcn_mfma_f32_16x16x32_bf16(
                    af[m], bfr[n], acc[m][n], 0, 0, 0);
        if (s < 7) __syncthreads();
    }

    const bool isL = (wcg < 256);
    ushort* OutP = isL ? xl : xr;
    const float* bvp = isL ? bl : br;
    const int cb0 = wcg & 255;

    int colLoc[8]; float bb[8];
#pragma unroll
    for (int n = 0; n < 8; ++n) {
        colLoc[n] = cb0 + n * 16 + (lane & 15);
        bb[n] = bvp[colLoc[n]];
    }
#pragma unroll
    for (int m = 0; m < 4; ++m) {
        int r0 = rowBase + wr + m * 16 + (lane >> 4) * 4;
#pragma unroll
        for (int r = 0; r < 4; ++r) {
            int row = r0 + r;
            if (row < NN) {
#pragma unroll
                for (int n = 0; n < 8; ++n)
                    OutP[(size_t)row * 256 + colLoc[n]] = f2b(acc[m][n][r] + bb[n]);
            }
        }
    }
}

// ------- fused scan: each block sums its prefix directly, then local scan --
__global__ __launch_bounds__(256) void scan_fused(const int* __restrict__ cnt,
                                                  int* __restrict__ rowptr)
{
    __shared__ int red[256];
    __shared__ int pre[256];
    int tb = threadIdx.x;

    const int4* c4 = reinterpret_cast<const int4*>(cnt);
    int lim4 = blockIdx.x * 256;            // (blockIdx.x*1024)/4
    int s0 = 0;
    for (int i = tb; i < lim4; i += 256) {
        int4 v = c4[i];
        s0 += v.x + v.y + v.z + v.w;
    }
    red[tb] = s0; __syncthreads();
    for (int off = 128; off > 0; off >>= 1) {
        if (tb < off) red[tb] += red[tb + off];
        __syncthreads();
    }
    int base0 = red[0];

    int base = blockIdx.x * 1024 + tb * 4;
    int v[4]; int s = 0;
#pragma unroll
    for (int k = 0; k < 4; ++k) { int i = base + k; v[k] = (i < NN) ? cnt[i] : 0; s += v[k]; }
    pre[tb] = s; __syncthreads();
    for (int off = 1; off < 256; off <<= 1) {
        int tv = (tb >= off) ? pre[tb - off] : 0;
        __syncthreads();
        pre[tb] += tv;
        __syncthreads();
    }
    int excl = pre[tb] - s + base0;
#pragma unroll
    for (int k = 0; k < 4; ++k) {
        int i = base + k;
        if (i < NN) { rowptr[i] = excl; excl += v[k]; }
    }
}

// fill: rowptr doubles as cursor; post-fill rowptr[n] == orig rowptr[n+1]
__global__ __launch_bounds__(256) void fill_csr(const int* __restrict__ src,
                                                const int* __restrict__ dst,
                                                int* __restrict__ rowptr,
                                                int* __restrict__ srcs)
{
    int e = blockIdx.x * 256 + threadIdx.x;
    if (e >= EE) return;
    int pos = atomicAdd(&rowptr[dst[e]], 1);
    srcs[pos] = src[e];
}

// ------------- fused: score + softmax-agg + bias + residual + LN + ELU -----
// one wave per node; srcs via lane-window + shfl (R12 form: VGPR 36)
__global__ __launch_bounds__(256) void aggregate_finalize(
    const ushort* __restrict__ xl, const ushort* __restrict__ xr,
    const int* __restrict__ srcs, const int* __restrict__ rowptr,
    const float* __restrict__ att, const ushort* __restrict__ xb,
    const float* __restrict__ bias, const float* __restrict__ gamma,
    const float* __restrict__ beta, float* __restrict__ out)
{
    int node = blockIdx.x * 4 + (threadIdx.x >> 6);
    if (node >= NN) return;
    int lane = threadIdx.x & 63;
    int half = lane >> 5;
    int dl = lane & 31;          // dims [dl*8, dl*8+8)
    const int off = dl * 8;

    uint4 xru = *reinterpret_cast<const uint4*>(xr + (size_t)node * DALL + off);
    float xrv[8]; unpack8(xru, xrv);
    float atv[8];
    {
        float4 a0 = *reinterpret_cast<const float4*>(att + off);
        float4 a1 = *reinterpret_cast<const float4*>(att + off + 4);
        atv[0]=a0.x; atv[1]=a0.y; atv[2]=a0.z; atv[3]=a0.w;
        atv[4]=a1.x; atv[5]=a1.y; atv[6]=a1.z; atv[7]=a1.w;
    }

    int beg = node ? rowptr[node - 1] : 0;
    int end = rowptr[node];
    float a[8] = {0.f,0.f,0.f,0.f,0.f,0.f,0.f,0.f};
    float dsum = 0.f;

    for (int wbase = beg; wbase < end; wbase += 64) {
        int wdeg = end - wbase; if (wdeg > 64) wdeg = 64;
        int sidx = wbase + lane; if (sidx > EE - 1) sidx = EE - 1;
        int srcs_l = srcs[sidx];      // one load covers the whole window

        for (int rb = 0; rb < wdeg; rb += 4) {
            int rA = rb + half;
            int rB = rb + 2 + half;
            bool vA = rA < wdeg, vB = rB < wdeg;
            int sA = __shfl(srcs_l, vA ? rA : 0);
            int sB = __shfl(srcs_l, vB ? rB : 0);
            uint4 gA = *reinterpret_cast<const uint4*>(xl + (size_t)sA * DALL + off);
            uint4 gB = *reinterpret_cast<const uint4*>(xl + (size_t)sB * DALL + off);
            float vAv[8], vBv[8]; unpack8(gA, vAv); unpack8(gB, vBv);
            float pA = 0.f, pB = 0.f;
#pragma unroll
            for (int i = 0; i < 8; ++i) {
                // lrelu(z) = max(z, 0.2z)
                float z = vAv[i] + xrv[i];  pA += fmaxf(z, NEG * z) * atv[i];
                float z2 = vBv[i] + xrv[i]; pB += fmaxf(z2, NEG * z2) * atv[i];
            }
            pA += __shfl_xor(pA, 1); pA += __shfl_xor(pA, 2);
            pB += __shfl_xor(pB, 1); pB += __shfl_xor(pB, 2);
            float peA = vA ? __expf(pA) : 0.f;
            float peB = vB ? __expf(pB) : 0.f;
#pragma unroll
            for (int i = 0; i < 8; ++i) a[i] += peA * vAv[i] + peB * vBv[i];
            dsum += peA + peB;
        }
    }

#pragma unroll
    for (int i = 0; i < 8; ++i) a[i] += __shfl_xor(a[i], 32);
    dsum += __shfl_xor(dsum, 32);
    float inv = dsum > 0.f ? 1.f / dsum : 0.f;

    uint4 xbu = *reinterpret_cast<const uint4*>(xb + (size_t)node * DALL + off);
    float xv[8]; unpack8(xbu, xv);
    float bvv[8], gvv[8], bev[8];
    {
        float4 b0 = *reinterpret_cast<const float4*>(bias + off);
        float4 b1 = *reinterpret_cast<const float4*>(bias + off + 4);
        bvv[0]=b0.x; bvv[1]=b0.y; bvv[2]=b0.z; bvv[3]=b0.w;
        bvv[4]=b1.x; bvv[5]=b1.y; bvv[6]=b1.z; bvv[7]=b1.w;
        float4 g0 = *reinterpret_cast<const float4*>(gamma + off);
        float4 g1 = *reinterpret_cast<const float4*>(gamma + off + 4);
        gvv[0]=g0.x; gvv[1]=g0.y; gvv[2]=g0.z; gvv[3]=g0.w;
        gvv[4]=g1.x; gvv[5]=g1.y; gvv[6]=g1.z; gvv[7]=g1.w;
        float4 e0 = *reinterpret_cast<const float4*>(beta + off);
        float4 e1 = *reinterpret_cast<const float4*>(beta + off + 4);
        bev[0]=e0.x; bev[1]=e0.y; bev[2]=e0.z; bev[3]=e0.w;
        bev[4]=e1.x; bev[5]=e1.y; bev[6]=e1.z; bev[7]=e1.w;
    }

    float y[8]; float sum = 0.f, sq = 0.f;
#pragma unroll
    for (int i = 0; i < 8; ++i) {
        y[i] = a[i] * inv + bvv[i] + xv[i];
        sum += y[i]; sq += y[i] * y[i];
    }
#pragma unroll
    for (int m = 1; m < 32; m <<= 1) {
        sum += __shfl_xor(sum, m);
        sq  += __shfl_xor(sq, m);
    }
    float mu  = sum * (1.0f / 256.0f);
    float var = sq * (1.0f / 256.0f) - mu * mu;
    float rr  = rsqrtf(var + 1e-5f);

    if (half == 0) {
        f32x4 o0, o1;
#pragma unroll
        for (int i = 0; i < 8; ++i) {
            float z = (y[i] - mu) * rr * gvv[i] + bev[i];
            float e = z > 0.f ? z : __expf(z) - 1.f;   // ELU via fast exp
            if (i < 4) o0[i] = e; else o1[i - 4] = e;
        }
        __builtin_nontemporal_store(o0,
            reinterpret_cast<f32x4*>(out + (size_t)node * DALL + off));
        __builtin_nontemporal_store(o1,
            reinterpret_cast<f32x4*>(out + (size_t)node * DALL + off + 4));
    }
}

extern "C" void kernel_launch(void* const* d_in, const int* in_sizes, int n_in,
                              void* d_out, int out_size, void* d_ws, size_t ws_size,
                              hipStream_t stream)
{
    const float* x    = (const float*)d_in[0];
    const int*   edge = (const int*)d_in[1];
    const float* Wl   = (const float*)d_in[2];
    const float* bl   = (const float*)d_in[3];
    const float* Wr   = (const float*)d_in[4];
    const float* br   = (const float*)d_in[5];
    const float* att  = (const float*)d_in[6];
    const float* bias = (const float*)d_in[7];
    const float* gamma= (const float*)d_in[8];
    const float* beta = (const float*)d_in[9];
    float* out = (float*)d_out;

    const int* srcIdx = edge;
    const int* dstIdx = edge + EE;

    ushort* xl = (ushort*)d_ws;                     // NN*256 bf16
    ushort* xr = xl + (size_t)NN * DALL;            // NN*256 bf16
    ushort* xb = xr + (size_t)NN * DALL;            // NN*256 bf16
    ushort* Wt = xb + (size_t)NN * DALL;            // 512*256 bf16
    int* rowptr = (int*)(Wt + 512 * 256);           // NN
    int* cnt    = rowptr + NN + 1;                  // NN
    int* srcs   = cnt + NN;                         // EE

    const int SCAN_NB = (NN + 1023) / 1024;         // 98

    hipMemsetAsync(cnt, 0, NN * sizeof(int), stream);
    fused_init<<<CNT_BLOCKS + CVTW_BLOCKS + CVTX_BLOCKS, 256, 0, stream>>>(
        x, Wl, Wr, dstIdx, xb, Wt, cnt);
    gemm_dual<<<(NN + 127) / 128, 512, 0, stream>>>(xb, Wt, bl, br, xl, xr);
    scan_fused<<<SCAN_NB, 256, 0, stream>>>(cnt, rowptr);
    fill_csr<<<(EE + 255) / 256, 256, 0, stream>>>(srcIdx, dstIdx, rowptr, srcs);
    aggregate_finalize<<<NN / 4, 256, 0, stream>>>(
        xl, xr, srcs, rowptr, att, xb, bias, gamma, beta, out);
}

// Round 17
// 266.151 us; speedup vs baseline: 1.1038x; 1.0495x over previous
//
#include <hip/hip_runtime.h>
#include <hip/hip_bf16.h>

#define NN 100000
#define EE 800000
#define DALL 256
#define NEG 0.2f

#define CNT_BLOCKS 3125     // ceil(EE/256)
#define CVTW_BLOCKS 128     // 8 x 16
#define CVTX_BLOCKS 2048

#define GEMM_BLOCKS 782     // ceil(NN/128)
#define SCAN_NB 98          // ceil(NN/1024)

typedef __attribute__((ext_vector_type(8))) short bf16x8;
typedef __attribute__((ext_vector_type(4))) float f32x4;

static __device__ __forceinline__ ushort f2b(float f) {
    __hip_bfloat16 h = __float2bfloat16(f);
    return *reinterpret_cast<ushort*>(&h);
}
static __device__ __forceinline__ float b2f(ushort u) {
    union { float f; unsigned v; } c; c.v = ((unsigned)u) << 16; return c.f;
}
static __device__ __forceinline__ void unpack8(uint4 u, float* v) {
    v[0] = b2f((ushort)(u.x & 0xffff)); v[1] = b2f((ushort)(u.x >> 16));
    v[2] = b2f((ushort)(u.y & 0xffff)); v[3] = b2f((ushort)(u.y >> 16));
    v[4] = b2f((ushort)(u.z & 0xffff)); v[5] = b2f((ushort)(u.z >> 16));
    v[6] = b2f((ushort)(u.w & 0xffff)); v[7] = b2f((ushort)(u.w >> 16));
}

// ---- fused init: count_deg | cvt_W | cvt_x, partitioned by blockIdx -------
__global__ __launch_bounds__(256) void fused_init(
    const float* __restrict__ x, const float* __restrict__ Wl,
    const float* __restrict__ Wr, const int* __restrict__ dst,
    ushort* __restrict__ xb, ushort* __restrict__ Wt, int* __restrict__ cnt)
{
    __shared__ float tile[32][33];
    int b = blockIdx.x;
    if (b < CNT_BLOCKS) {
        int e = b * 256 + threadIdx.x;
        if (e < EE) atomicAdd(&cnt[dst[e]], 1);
        return;
    }
    b -= CNT_BLOCKS;
    if (b < CVTW_BLOCKS) {
        int kt = (b & 7) * 32, nt = (b >> 3) * 32;
        int tx = threadIdx.x & 31, ty = threadIdx.x >> 5;
#pragma unroll
        for (int i = 0; i < 32; i += 8) {
            int k = kt + ty + i, n = nt + tx;
            float v = (n < 256) ? Wl[(size_t)k * 256 + n] : Wr[(size_t)k * 256 + (n - 256)];
            tile[ty + i][tx] = v;
        }
        __syncthreads();
#pragma unroll
        for (int i = 0; i < 32; i += 8) {
            int n = nt + ty + i, k = kt + tx;
            Wt[(size_t)n * 256 + k] = f2b(tile[tx][ty + i]);
        }
        return;
    }
    b -= CVTW_BLOCKS;
    const int total = NN * DALL / 8;
    for (int i = b * 256 + threadIdx.x; i < total; i += CVTX_BLOCKS * 256) {
        f32x4 a = __builtin_nontemporal_load(reinterpret_cast<const f32x4*>(x) + i * 2);
        f32x4 c = __builtin_nontemporal_load(reinterpret_cast<const f32x4*>(x) + i * 2 + 1);
        uint4 o;
        o.x = f2b(a[0]) | ((unsigned)f2b(a[1]) << 16);
        o.y = f2b(a[2]) | ((unsigned)f2b(a[3]) << 16);
        o.z = f2b(c[0]) | ((unsigned)f2b(c[1]) << 16);
        o.w = f2b(c[2]) | ((unsigned)f2b(c[3]) << 16);
        reinterpret_cast<uint4*>(xb)[i] = o;
    }
}

// ---- phase2: GEMM (blocks 0..781) | fused scan (blocks 782..879) ----------
// GEMM: 128 rows x 512 cols per block, 8 waves, A panel read exactly once.
// Scan blocks alias their 2KB of LDS into smemA (no extra LDS -> occupancy).
__global__ __launch_bounds__(512) void phase2(
    const ushort* __restrict__ xb,   // [NN][256] bf16
    const ushort* __restrict__ Wt,   // [512][256] bf16 (B^T layout)
    const float* __restrict__ bl, const float* __restrict__ br,
    ushort* __restrict__ xl, ushort* __restrict__ xr,
    const int* __restrict__ cnt, int* __restrict__ rowptr)
{
    __shared__ __align__(16) ushort smemA[2][128 * 32];   // 8KB/buf
    __shared__ __align__(16) ushort smemB[2][512 * 32];   // 32KB/buf

    const int bx = blockIdx.x;
    const int t = threadIdx.x;

    if (bx >= GEMM_BLOCKS) {
        // ---------------- scan partition ----------------
        const int sb = bx - GEMM_BLOCKS;        // 0..97
        int* red = reinterpret_cast<int*>(&smemA[0][0]);        // 256 ints
        int* pre = red + 256;                                   // 256 ints

        // prefix base: sum of cnt[0 .. sb*1024), int4-vectorized, L2-hot
        int s0 = 0;
        if (t < 256) {
            const int4* c4 = reinterpret_cast<const int4*>(cnt);
            int lim4 = sb * 256;
            for (int i = t; i < lim4; i += 256) {
                int4 v = c4[i];
                s0 += v.x + v.y + v.z + v.w;
            }
            red[t] = s0;
        }
        __syncthreads();
        for (int off = 128; off > 0; off >>= 1) {
            if (t < off) red[t] += red[t + off];
            __syncthreads();
        }
        int base0 = red[0];

        int base = sb * 1024 + t * 4;
        int v[4]; int s = 0;
        if (t < 256) {
#pragma unroll
            for (int k = 0; k < 4; ++k) { int i = base + k; v[k] = (i < NN) ? cnt[i] : 0; s += v[k]; }
            pre[t] = s;
        }
        __syncthreads();
        for (int off = 1; off < 256; off <<= 1) {
            int tv = (t >= off && t < 256) ? pre[t - off] : 0;
            __syncthreads();
            if (t < 256) pre[t] += tv;
            __syncthreads();
        }
        if (t < 256) {
            int excl = pre[t] - s + base0;
#pragma unroll
            for (int k = 0; k < 4; ++k) {
                int i = base + k;
                if (i < NN) { rowptr[i] = excl; excl += v[k]; }
            }
        }
        return;
    }

    // ---------------- GEMM partition ----------------
    const int rowBase = bx * 128;
    const int lane = t & 63, wave = t >> 6;
    const int wr  = (wave >> 2) * 64;     // 2 row groups (0,64)
    const int wcg = (wave & 3) * 128;     // 4 col groups (0,128,256,384)

    f32x4 acc[4][8];
#pragma unroll
    for (int m = 0; m < 4; ++m)
#pragma unroll
        for (int n = 0; n < 8; ++n) acc[m][n] = (f32x4){0.f, 0.f, 0.f, 0.f};

    auto STAGE = [&](int buf, int kb) {
        {   // A: 128x32 = 512 chunks of 16B, 1/thread
            int rc = t >> 2, slot = t & 3;
            int ga = rowBase + rc; if (ga >= NN) ga = NN - 1;
            const ushort* gp = xb + (size_t)ga * 256 + kb + slot * 8;
            ushort* lp = &smemA[buf][wave * 512];
            __builtin_amdgcn_global_load_lds(
                (const __attribute__((address_space(1))) unsigned int*)gp,
                (__attribute__((address_space(3))) unsigned int*)lp, 16, 0, 0);
        }
#pragma unroll
        for (int i = 0; i < 4; ++i) {   // B: 512x32 = 2048 chunks, 4/thread
            int c = i * 512 + t;
            int rc = c >> 2, slot = c & 3;
            const ushort* gp = Wt + (size_t)rc * 256 + kb + slot * 8;
            ushort* lp = &smemB[buf][(i * 512 + wave * 64) * 8];
            __builtin_amdgcn_global_load_lds(
                (const __attribute__((address_space(1))) unsigned int*)gp,
                (__attribute__((address_space(3))) unsigned int*)lp, 16, 0, 0);
        }
    };

    STAGE(0, 0);
    __syncthreads();

#pragma unroll
    for (int s = 0; s < 8; ++s) {
        if (s < 7) STAGE((s + 1) & 1, (s + 1) * 32);
        const ushort* A = smemA[s & 1];
        const ushort* B = smemB[s & 1];
        bf16x8 af[4], bfr[8];
#pragma unroll
        for (int m = 0; m < 4; ++m)
            af[m] = *reinterpret_cast<const bf16x8*>(
                &A[(wr + m * 16 + (lane & 15)) * 32 + (lane >> 4) * 8]);
#pragma unroll
        for (int n = 0; n < 8; ++n)
            bfr[n] = *reinterpret_cast<const bf16x8*>(
                &B[(wcg + n * 16 + (lane & 15)) * 32 + (lane >> 4) * 8]);
#pragma unroll
        for (int m = 0; m < 4; ++m)
#pragma unroll
            for (int n = 0; n < 8; ++n)
                acc[m][n] = __builtin_amdgcn_mfma_f32_16x16x32_bf16(
                    af[m], bfr[n], acc[m][n], 0, 0, 0);
        if (s < 7) __syncthreads();
    }

    const bool isL = (wcg < 256);
    ushort* OutP = isL ? xl : xr;
    const float* bvp = isL ? bl : br;
    const int cb0 = wcg & 255;

    int colLoc[8]; float bb[8];
#pragma unroll
    for (int n = 0; n < 8; ++n) {
        colLoc[n] = cb0 + n * 16 + (lane & 15);
        bb[n] = bvp[colLoc[n]];
    }
#pragma unroll
    for (int m = 0; m < 4; ++m) {
        int r0 = rowBase + wr + m * 16 + (lane >> 4) * 4;
#pragma unroll
        for (int r = 0; r < 4; ++r) {
            int row = r0 + r;
            if (row < NN) {
#pragma unroll
                for (int n = 0; n < 8; ++n)
                    OutP[(size_t)row * 256 + colLoc[n]] = f2b(acc[m][n][r] + bb[n]);
            }
        }
    }
}

// fill: rowptr doubles as cursor; post-fill rowptr[n] == orig rowptr[n+1]
__global__ __launch_bounds__(256) void fill_csr(const int* __restrict__ src,
                                                const int* __restrict__ dst,
                                                int* __restrict__ rowptr,
                                                int* __restrict__ srcs)
{
    int e = blockIdx.x * 256 + threadIdx.x;
    if (e >= EE) return;
    int pos = atomicAdd(&rowptr[dst[e]], 1);
    srcs[pos] = src[e];
}

// ------------- fused: score + softmax-agg + bias + residual + LN + ELU -----
// one wave per node; srcs via lane-window + shfl (frozen R12 form: VGPR 36)
__global__ __launch_bounds__(256) void aggregate_finalize(
    const ushort* __restrict__ xl, const ushort* __restrict__ xr,
    const int* __restrict__ srcs, const int* __restrict__ rowptr,
    const float* __restrict__ att, const ushort* __restrict__ xb,
    const float* __restrict__ bias, const float* __restrict__ gamma,
    const float* __restrict__ beta, float* __restrict__ out)
{
    int node = blockIdx.x * 4 + (threadIdx.x >> 6);
    if (node >= NN) return;
    int lane = threadIdx.x & 63;
    int half = lane >> 5;
    int dl = lane & 31;          // dims [dl*8, dl*8+8)
    const int off = dl * 8;

    uint4 xru = *reinterpret_cast<const uint4*>(xr + (size_t)node * DALL + off);
    float xrv[8]; unpack8(xru, xrv);
    float atv[8];
    {
        float4 a0 = *reinterpret_cast<const float4*>(att + off);
        float4 a1 = *reinterpret_cast<const float4*>(att + off + 4);
        atv[0]=a0.x; atv[1]=a0.y; atv[2]=a0.z; atv[3]=a0.w;
        atv[4]=a1.x; atv[5]=a1.y; atv[6]=a1.z; atv[7]=a1.w;
    }

    int beg = node ? rowptr[node - 1] : 0;
    int end = rowptr[node];
    float a[8] = {0.f,0.f,0.f,0.f,0.f,0.f,0.f,0.f};
    float dsum = 0.f;

    for (int wbase = beg; wbase < end; wbase += 64) {
        int wdeg = end - wbase; if (wdeg > 64) wdeg = 64;
        int sidx = wbase + lane; if (sidx > EE - 1) sidx = EE - 1;
        int srcs_l = srcs[sidx];      // one load covers the whole window

        for (int rb = 0; rb < wdeg; rb += 4) {
            int rA = rb + half;
            int rB = rb + 2 + half;
            bool vA = rA < wdeg, vB = rB < wdeg;
            int sA = __shfl(srcs_l, vA ? rA : 0);
            int sB = __shfl(srcs_l, vB ? rB : 0);
            uint4 gA = *reinterpret_cast<const uint4*>(xl + (size_t)sA * DALL + off);
            uint4 gB = *reinterpret_cast<const uint4*>(xl + (size_t)sB * DALL + off);
            float vAv[8], vBv[8]; unpack8(gA, vAv); unpack8(gB, vBv);
            float pA = 0.f, pB = 0.f;
#pragma unroll
            for (int i = 0; i < 8; ++i) {
                // lrelu(z) = max(z, 0.2z)
                float z = vAv[i] + xrv[i];  pA += fmaxf(z, NEG * z) * atv[i];
                float z2 = vBv[i] + xrv[i]; pB += fmaxf(z2, NEG * z2) * atv[i];
            }
            pA += __shfl_xor(pA, 1); pA += __shfl_xor(pA, 2);
            pB += __shfl_xor(pB, 1); pB += __shfl_xor(pB, 2);
            float peA = vA ? __expf(pA) : 0.f;
            float peB = vB ? __expf(pB) : 0.f;
#pragma unroll
            for (int i = 0; i < 8; ++i) a[i] += peA * vAv[i] + peB * vBv[i];
            dsum += peA + peB;
        }
    }

#pragma unroll
    for (int i = 0; i < 8; ++i) a[i] += __shfl_xor(a[i], 32);
    dsum += __shfl_xor(dsum, 32);
    float inv = dsum > 0.f ? 1.f / dsum : 0.f;

    uint4 xbu = *reinterpret_cast<const uint4*>(xb + (size_t)node * DALL + off);
    float xv[8]; unpack8(xbu, xv);
    float bvv[8], gvv[8], bev[8];
    {
        float4 b0 = *reinterpret_cast<const float4*>(bias + off);
        float4 b1 = *reinterpret_cast<const float4*>(bias + off + 4);
        bvv[0]=b0.x; bvv[1]=b0.y; bvv[2]=b0.z; bvv[3]=b0.w;
        bvv[4]=b1.x; bvv[5]=b1.y; bvv[6]=b1.z; bvv[7]=b1.w;
        float4 g0 = *reinterpret_cast<const float4*>(gamma + off);
        float4 g1 = *reinterpret_cast<const float4*>(gamma + off + 4);
        gvv[0]=g0.x; gvv[1]=g0.y; gvv[2]=g0.z; gvv[3]=g0.w;
        gvv[4]=g1.x; gvv[5]=g1.y; gvv[6]=g1.z; gvv[7]=g1.w;
        float4 e0 = *reinterpret_cast<const float4*>(beta + off);
        float4 e1 = *reinterpret_cast<const float4*>(beta + off + 4);
        bev[0]=e0.x; bev[1]=e0.y; bev[2]=e0.z; bev[3]=e0.w;
        bev[4]=e1.x; bev[5]=e1.y; bev[6]=e1.z; bev[7]=e1.w;
    }

    float y[8]; float sum = 0.f, sq = 0.f;
#pragma unroll
    for (int i = 0; i < 8; ++i) {
        y[i] = a[i] * inv + bvv[i] + xv[i];
        sum += y[i]; sq += y[i] * y[i];
    }
#pragma unroll
    for (int m = 1; m < 32; m <<= 1) {
        sum += __shfl_xor(sum, m);
        sq  += __shfl_xor(sq, m);
    }
    float mu  = sum * (1.0f / 256.0f);
    float var = sq * (1.0f / 256.0f) - mu * mu;
    float rr  = rsqrtf(var + 1e-5f);

    if (half == 0) {
        f32x4 o0, o1;
#pragma unroll
        for (int i = 0; i < 8; ++i) {
            float z = (y[i] - mu) * rr * gvv[i] + bev[i];
            float e = z > 0.f ? z : __expf(z) - 1.f;   // ELU via fast exp
            if (i < 4) o0[i] = e; else o1[i - 4] = e;
        }
        __builtin_nontemporal_store(o0,
            reinterpret_cast<f32x4*>(out + (size_t)node * DALL + off));
        __builtin_nontemporal_store(o1,
            reinterpret_cast<f32x4*>(out + (size_t)node * DALL + off + 4));
    }
}

extern "C" void kernel_launch(void* const* d_in, const int* in_sizes, int n_in,
                              void* d_out, int out_size, void* d_ws, size_t ws_size,
                              hipStream_t stream)
{
    const float* x    = (const float*)d_in[0];
    const int*   edge = (const int*)d_in[1];
    const float* Wl   = (const float*)d_in[2];
    const float* bl   = (const float*)d_in[3];
    const float* Wr   = (const float*)d_in[4];
    const float* br   = (const float*)d_in[5];
    const float* att  = (const float*)d_in[6];
    const float* bias = (const float*)d_in[7];
    const float* gamma= (const float*)d_in[8];
    const float* beta = (const float*)d_in[9];
    float* out = (float*)d_out;

    const int* srcIdx = edge;
    const int* dstIdx = edge + EE;

    ushort* xl = (ushort*)d_ws;                     // NN*256 bf16
    ushort* xr = xl + (size_t)NN * DALL;            // NN*256 bf16
    ushort* xb = xr + (size_t)NN * DALL;            // NN*256 bf16
    ushort* Wt = xb + (size_t)NN * DALL;            // 512*256 bf16
    int* rowptr = (int*)(Wt + 512 * 256);           // NN
    int* cnt    = rowptr + NN + 1;                  // NN
    int* srcs   = cnt + NN;                         // EE

    hipMemsetAsync(cnt, 0, NN * sizeof(int), stream);
    fused_init<<<CNT_BLOCKS + CVTW_BLOCKS + CVTX_BLOCKS, 256, 0, stream>>>(
        x, Wl, Wr, dstIdx, xb, Wt, cnt);
    phase2<<<GEMM_BLOCKS + SCAN_NB, 512, 0, stream>>>(
        xb, Wt, bl, br, xl, xr, cnt, rowptr);
    fill_csr<<<(EE + 255) / 256, 256, 0, stream>>>(srcIdx, dstIdx, rowptr, srcs);
    aggregate_finalize<<<NN / 4, 256, 0, stream>>>(
        xl, xr, srcs, rowptr, att, xb, bias, gamma, beta, out);
}

// Round 18
// 247.685 us; speedup vs baseline: 1.1861x; 1.0746x over previous
//
#include <hip/hip_runtime.h>
#include <hip/hip_bf16.h>

#define NN 100000
#define EE 800000
#define DALL 256
#define NEG 0.2f

#define CNT_BLOCKS 3125     // ceil(EE/256)
#define CVTW_BLOCKS 128     // 8 x 16
#define CVTX_BLOCKS 2048

#define GEMM_BLOCKS 782     // ceil(NN/128)
#define SCAN_NB 98          // ceil(NN/1024)

typedef __attribute__((ext_vector_type(8))) short bf16x8;
typedef __attribute__((ext_vector_type(4))) float f32x4;

static __device__ __forceinline__ ushort f2b(float f) {
    __hip_bfloat16 h = __float2bfloat16(f);
    return *reinterpret_cast<ushort*>(&h);
}
static __device__ __forceinline__ float b2f(ushort u) {
    union { float f; unsigned v; } c; c.v = ((unsigned)u) << 16; return c.f;
}
static __device__ __forceinline__ void unpack8(uint4 u, float* v) {
    v[0] = b2f((ushort)(u.x & 0xffff)); v[1] = b2f((ushort)(u.x >> 16));
    v[2] = b2f((ushort)(u.y & 0xffff)); v[3] = b2f((ushort)(u.y >> 16));
    v[4] = b2f((ushort)(u.z & 0xffff)); v[5] = b2f((ushort)(u.z >> 16));
    v[6] = b2f((ushort)(u.w & 0xffff)); v[7] = b2f((ushort)(u.w >> 16));
}

// ---- fused init: count_deg(+eoff) | cvt_W | cvt_x, blockIdx-partitioned ---
__global__ __launch_bounds__(256) void fused_init(
    const float* __restrict__ x, const float* __restrict__ Wl,
    const float* __restrict__ Wr, const int* __restrict__ dst,
    ushort* __restrict__ xb, ushort* __restrict__ Wt, int* __restrict__ cnt,
    int* __restrict__ eoff)
{
    __shared__ float tile[32][33];
    int b = blockIdx.x;
    if (b < CNT_BLOCKS) {
        int e = b * 256 + threadIdx.x;
        if (e < EE) {
            // capture the per-edge slot within its dst bucket (was discarded)
            eoff[e] = atomicAdd(&cnt[dst[e]], 1);
        }
        return;
    }
    b -= CNT_BLOCKS;
    if (b < CVTW_BLOCKS) {
        int kt = (b & 7) * 32, nt = (b >> 3) * 32;
        int tx = threadIdx.x & 31, ty = threadIdx.x >> 5;
#pragma unroll
        for (int i = 0; i < 32; i += 8) {
            int k = kt + ty + i, n = nt + tx;
            float v = (n < 256) ? Wl[(size_t)k * 256 + n] : Wr[(size_t)k * 256 + (n - 256)];
            tile[ty + i][tx] = v;
        }
        __syncthreads();
#pragma unroll
        for (int i = 0; i < 32; i += 8) {
            int n = nt + ty + i, k = kt + tx;
            Wt[(size_t)n * 256 + k] = f2b(tile[tx][ty + i]);
        }
        return;
    }
    b -= CVTW_BLOCKS;
    const int total = NN * DALL / 8;
    for (int i = b * 256 + threadIdx.x; i < total; i += CVTX_BLOCKS * 256) {
        f32x4 a = __builtin_nontemporal_load(reinterpret_cast<const f32x4*>(x) + i * 2);
        f32x4 c = __builtin_nontemporal_load(reinterpret_cast<const f32x4*>(x) + i * 2 + 1);
        uint4 o;
        o.x = f2b(a[0]) | ((unsigned)f2b(a[1]) << 16);
        o.y = f2b(a[2]) | ((unsigned)f2b(a[3]) << 16);
        o.z = f2b(c[0]) | ((unsigned)f2b(c[1]) << 16);
        o.w = f2b(c[2]) | ((unsigned)f2b(c[3]) << 16);
        reinterpret_cast<uint4*>(xb)[i] = o;
    }
}

// ---- phase2: GEMM (blocks 0..781) | fused scan (blocks 782..879) ----------
__global__ __launch_bounds__(512) void phase2(
    const ushort* __restrict__ xb,   // [NN][256] bf16
    const ushort* __restrict__ Wt,   // [512][256] bf16 (B^T layout)
    const float* __restrict__ bl, const float* __restrict__ br,
    ushort* __restrict__ xl, ushort* __restrict__ xr,
    const int* __restrict__ cnt, int* __restrict__ rowptr)
{
    __shared__ __align__(16) ushort smemA[2][128 * 32];   // 8KB/buf
    __shared__ __align__(16) ushort smemB[2][512 * 32];   // 32KB/buf

    const int bx = blockIdx.x;
    const int t = threadIdx.x;

    if (bx >= GEMM_BLOCKS) {
        // ---------------- scan partition (exclusive; also rowptr[NN]=EE) ---
        const int sb = bx - GEMM_BLOCKS;        // 0..97
        int* red = reinterpret_cast<int*>(&smemA[0][0]);        // 256 ints
        int* pre = red + 256;                                   // 256 ints

        int s0 = 0;
        if (t < 256) {
            const int4* c4 = reinterpret_cast<const int4*>(cnt);
            int lim4 = sb * 256;
            for (int i = t; i < lim4; i += 256) {
                int4 v = c4[i];
                s0 += v.x + v.y + v.z + v.w;
            }
            red[t] = s0;
        }
        __syncthreads();
        for (int off = 128; off > 0; off >>= 1) {
            if (t < off) red[t] += red[t + off];
            __syncthreads();
        }
        int base0 = red[0];

        int base = sb * 1024 + t * 4;
        int v[4]; int s = 0;
        if (t < 256) {
#pragma unroll
            for (int k = 0; k < 4; ++k) { int i = base + k; v[k] = (i < NN) ? cnt[i] : 0; s += v[k]; }
            pre[t] = s;
        }
        __syncthreads();
        for (int off = 1; off < 256; off <<= 1) {
            int tv = (t >= off && t < 256) ? pre[t - off] : 0;
            __syncthreads();
            if (t < 256) pre[t] += tv;
            __syncthreads();
        }
        if (t < 256) {
            int excl = pre[t] - s + base0;
#pragma unroll
            for (int k = 0; k < 4; ++k) {
                int i = base + k;
                if (i < NN) { rowptr[i] = excl; excl += v[k]; }
            }
        }
        if (sb == SCAN_NB - 1 && t == 0) rowptr[NN] = EE;
        return;
    }

    // ---------------- GEMM partition ----------------
    const int rowBase = bx * 128;
    const int lane = t & 63, wave = t >> 6;
    const int wr  = (wave >> 2) * 64;     // 2 row groups (0,64)
    const int wcg = (wave & 3) * 128;     // 4 col groups (0,128,256,384)

    f32x4 acc[4][8];
#pragma unroll
    for (int m = 0; m < 4; ++m)
#pragma unroll
        for (int n = 0; n < 8; ++n) acc[m][n] = (f32x4){0.f, 0.f, 0.f, 0.f};

    auto STAGE = [&](int buf, int kb) {
        {   // A: 128x32 = 512 chunks of 16B, 1/thread
            int rc = t >> 2, slot = t & 3;
            int ga = rowBase + rc; if (ga >= NN) ga = NN - 1;
            const ushort* gp = xb + (size_t)ga * 256 + kb + slot * 8;
            ushort* lp = &smemA[buf][wave * 512];
            __builtin_amdgcn_global_load_lds(
                (const __attribute__((address_space(1))) unsigned int*)gp,
                (__attribute__((address_space(3))) unsigned int*)lp, 16, 0, 0);
        }
#pragma unroll
        for (int i = 0; i < 4; ++i) {   // B: 512x32 = 2048 chunks, 4/thread
            int c = i * 512 + t;
            int rc = c >> 2, slot = c & 3;
            const ushort* gp = Wt + (size_t)rc * 256 + kb + slot * 8;
            ushort* lp = &smemB[buf][(i * 512 + wave * 64) * 8];
            __builtin_amdgcn_global_load_lds(
                (const __attribute__((address_space(1))) unsigned int*)gp,
                (__attribute__((address_space(3))) unsigned int*)lp, 16, 0, 0);
        }
    };

    STAGE(0, 0);
    __syncthreads();

#pragma unroll
    for (int s = 0; s < 8; ++s) {
        if (s < 7) STAGE((s + 1) & 1, (s + 1) * 32);
        const ushort* A = smemA[s & 1];
        const ushort* B = smemB[s & 1];
        bf16x8 af[4], bfr[8];
#pragma unroll
        for (int m = 0; m < 4; ++m)
            af[m] = *reinterpret_cast<const bf16x8*>(
                &A[(wr + m * 16 + (lane & 15)) * 32 + (lane >> 4) * 8]);
#pragma unroll
        for (int n = 0; n < 8; ++n)
            bfr[n] = *reinterpret_cast<const bf16x8*>(
                &B[(wcg + n * 16 + (lane & 15)) * 32 + (lane >> 4) * 8]);
#pragma unroll
        for (int m = 0; m < 4; ++m)
#pragma unroll
            for (int n = 0; n < 8; ++n)
                acc[m][n] = __builtin_amdgcn_mfma_f32_16x16x32_bf16(
                    af[m], bfr[n], acc[m][n], 0, 0, 0);
        if (s < 7) __syncthreads();
    }

    const bool isL = (wcg < 256);
    ushort* OutP = isL ? xl : xr;
    const float* bvp = isL ? bl : br;
    const int cb0 = wcg & 255;

    int colLoc[8]; float bb[8];
#pragma unroll
    for (int n = 0; n < 8; ++n) {
        colLoc[n] = cb0 + n * 16 + (lane & 15);
        bb[n] = bvp[colLoc[n]];
    }
#pragma unroll
    for (int m = 0; m < 4; ++m) {
        int r0 = rowBase + wr + m * 16 + (lane >> 4) * 4;
#pragma unroll
        for (int r = 0; r < 4; ++r) {
            int row = r0 + r;
            if (row < NN) {
#pragma unroll
                for (int n = 0; n < 8; ++n)
                    OutP[(size_t)row * 256 + colLoc[n]] = f2b(acc[m][n][r] + bb[n]);
            }
        }
    }
}

// fill: ATOMIC-FREE — slot = rowptr[dst] + eoff (eoff captured in init)
__global__ __launch_bounds__(256) void fill_csr(const int* __restrict__ src,
                                                const int* __restrict__ dst,
                                                const int* __restrict__ rowptr,
                                                const int* __restrict__ eoff,
                                                int* __restrict__ srcs)
{
    int e = blockIdx.x * 256 + threadIdx.x;
    if (e >= EE) return;
    int d  = __builtin_nontemporal_load(dst + e);
    int sv = __builtin_nontemporal_load(src + e);
    int eo = __builtin_nontemporal_load(eoff + e);
    srcs[rowptr[d] + eo] = sv;          // rowptr: 400KB read-only, L2-hot
}

// ------------- fused: score + softmax-agg + bias + residual + LN + ELU -----
// one wave per node; srcs via lane-window + shfl (frozen R12 form: VGPR 36)
__global__ __launch_bounds__(256) void aggregate_finalize(
    const ushort* __restrict__ xl, const ushort* __restrict__ xr,
    const int* __restrict__ srcs, const int* __restrict__ rowptr,
    const float* __restrict__ att, const ushort* __restrict__ xb,
    const float* __restrict__ bias, const float* __restrict__ gamma,
    const float* __restrict__ beta, float* __restrict__ out)
{
    int node = blockIdx.x * 4 + (threadIdx.x >> 6);
    if (node >= NN) return;
    int lane = threadIdx.x & 63;
    int half = lane >> 5;
    int dl = lane & 31;          // dims [dl*8, dl*8+8)
    const int off = dl * 8;

    uint4 xru = *reinterpret_cast<const uint4*>(xr + (size_t)node * DALL + off);
    float xrv[8]; unpack8(xru, xrv);
    float atv[8];
    {
        float4 a0 = *reinterpret_cast<const float4*>(att + off);
        float4 a1 = *reinterpret_cast<const float4*>(att + off + 4);
        atv[0]=a0.x; atv[1]=a0.y; atv[2]=a0.z; atv[3]=a0.w;
        atv[4]=a1.x; atv[5]=a1.y; atv[6]=a1.z; atv[7]=a1.w;
    }

    int beg = rowptr[node];
    int end = rowptr[node + 1];
    float a[8] = {0.f,0.f,0.f,0.f,0.f,0.f,0.f,0.f};
    float dsum = 0.f;

    for (int wbase = beg; wbase < end; wbase += 64) {
        int wdeg = end - wbase; if (wdeg > 64) wdeg = 64;
        int sidx = wbase + lane; if (sidx > EE - 1) sidx = EE - 1;
        int srcs_l = srcs[sidx];      // one load covers the whole window

        for (int rb = 0; rb < wdeg; rb += 4) {
            int rA = rb + half;
            int rB = rb + 2 + half;
            bool vA = rA < wdeg, vB = rB < wdeg;
            int sA = __shfl(srcs_l, vA ? rA : 0);
            int sB = __shfl(srcs_l, vB ? rB : 0);
            uint4 gA = *reinterpret_cast<const uint4*>(xl + (size_t)sA * DALL + off);
            uint4 gB = *reinterpret_cast<const uint4*>(xl + (size_t)sB * DALL + off);
            float vAv[8], vBv[8]; unpack8(gA, vAv); unpack8(gB, vBv);
            float pA = 0.f, pB = 0.f;
#pragma unroll
            for (int i = 0; i < 8; ++i) {
                // lrelu(z) = max(z, 0.2z)
                float z = vAv[i] + xrv[i];  pA += fmaxf(z, NEG * z) * atv[i];
                float z2 = vBv[i] + xrv[i]; pB += fmaxf(z2, NEG * z2) * atv[i];
            }
            pA += __shfl_xor(pA, 1); pA += __shfl_xor(pA, 2);
            pB += __shfl_xor(pB, 1); pB += __shfl_xor(pB, 2);
            float peA = vA ? __expf(pA) : 0.f;
            float peB = vB ? __expf(pB) : 0.f;
#pragma unroll
            for (int i = 0; i < 8; ++i) a[i] += peA * vAv[i] + peB * vBv[i];
            dsum += peA + peB;
        }
    }

#pragma unroll
    for (int i = 0; i < 8; ++i) a[i] += __shfl_xor(a[i], 32);
    dsum += __shfl_xor(dsum, 32);
    float inv = dsum > 0.f ? 1.f / dsum : 0.f;

    uint4 xbu = *reinterpret_cast<const uint4*>(xb + (size_t)node * DALL + off);
    float xv[8]; unpack8(xbu, xv);
    float bvv[8], gvv[8], bev[8];
    {
        float4 b0 = *reinterpret_cast<const float4*>(bias + off);
        float4 b1 = *reinterpret_cast<const float4*>(bias + off + 4);
        bvv[0]=b0.x; bvv[1]=b0.y; bvv[2]=b0.z; bvv[3]=b0.w;
        bvv[4]=b1.x; bvv[5]=b1.y; bvv[6]=b1.z; bvv[7]=b1.w;
        float4 g0 = *reinterpret_cast<const float4*>(gamma + off);
        float4 g1 = *reinterpret_cast<const float4*>(gamma + off + 4);
        gvv[0]=g0.x; gvv[1]=g0.y; gvv[2]=g0.z; gvv[3]=g0.w;
        gvv[4]=g1.x; gvv[5]=g1.y; gvv[6]=g1.z; gvv[7]=g1.w;
        float4 e0 = *reinterpret_cast<const float4*>(beta + off);
        float4 e1 = *reinterpret_cast<const float4*>(beta + off + 4);
        bev[0]=e0.x; bev[1]=e0.y; bev[2]=e0.z; bev[3]=e0.w;
        bev[4]=e1.x; bev[5]=e1.y; bev[6]=e1.z; bev[7]=e1.w;
    }

    float y[8]; float sum = 0.f, sq = 0.f;
#pragma unroll
    for (int i = 0; i < 8; ++i) {
        y[i] = a[i] * inv + bvv[i] + xv[i];
        sum += y[i]; sq += y[i] * y[i];
    }
#pragma unroll
    for (int m = 1; m < 32; m <<= 1) {
        sum += __shfl_xor(sum, m);
        sq  += __shfl_xor(sq, m);
    }
    float mu  = sum * (1.0f / 256.0f);
    float var = sq * (1.0f / 256.0f) - mu * mu;
    float rr  = rsqrtf(var + 1e-5f);

    if (half == 0) {
        f32x4 o0, o1;
#pragma unroll
        for (int i = 0; i < 8; ++i) {
            float z = (y[i] - mu) * rr * gvv[i] + bev[i];
            float e = z > 0.f ? z : __expf(z) - 1.f;   // ELU via fast exp
            if (i < 4) o0[i] = e; else o1[i - 4] = e;
        }
        __builtin_nontemporal_store(o0,
            reinterpret_cast<f32x4*>(out + (size_t)node * DALL + off));
        __builtin_nontemporal_store(o1,
            reinterpret_cast<f32x4*>(out + (size_t)node * DALL + off + 4));
    }
}

extern "C" void kernel_launch(void* const* d_in, const int* in_sizes, int n_in,
                              void* d_out, int out_size, void* d_ws, size_t ws_size,
                              hipStream_t stream)
{
    const float* x    = (const float*)d_in[0];
    const int*   edge = (const int*)d_in[1];
    const float* Wl   = (const float*)d_in[2];
    const float* bl   = (const float*)d_in[3];
    const float* Wr   = (const float*)d_in[4];
    const float* br   = (const float*)d_in[5];
    const float* att  = (const float*)d_in[6];
    const float* bias = (const float*)d_in[7];
    const float* gamma= (const float*)d_in[8];
    const float* beta = (const float*)d_in[9];
    float* out = (float*)d_out;

    const int* srcIdx = edge;
    const int* dstIdx = edge + EE;

    ushort* xl = (ushort*)d_ws;                     // NN*256 bf16
    ushort* xr = xl + (size_t)NN * DALL;            // NN*256 bf16
    ushort* xb = xr + (size_t)NN * DALL;            // NN*256 bf16
    ushort* Wt = xb + (size_t)NN * DALL;            // 512*256 bf16
    int* rowptr = (int*)(Wt + 512 * 256);           // NN+1
    int* cnt    = rowptr + NN + 1;                  // NN
    int* srcs   = cnt + NN;                         // EE
    int* eoff   = srcs + EE;                        // EE

    hipMemsetAsync(cnt, 0, NN * sizeof(int), stream);
    fused_init<<<CNT_BLOCKS + CVTW_BLOCKS + CVTX_BLOCKS, 256, 0, stream>>>(
        x, Wl, Wr, dstIdx, xb, Wt, cnt, eoff);
    phase2<<<GEMM_BLOCKS + SCAN_NB, 512, 0, stream>>>(
        xb, Wt, bl, br, xl, xr, cnt, rowptr);
    fill_csr<<<(EE + 255) / 256, 256, 0, stream>>>(srcIdx, dstIdx, rowptr, eoff, srcs);
    aggregate_finalize<<<NN / 4, 256, 0, stream>>>(
        xl, xr, srcs, rowptr, att, xb, bias, gamma, beta, out);
}